// Round 26
// baseline (44.636 us; speedup 1.0000x reference)
//
#include <hip/hip_runtime.h>

typedef unsigned char u8;
typedef float f32x4 __attribute__((ext_vector_type(4)));
typedef _Float16 f16x8 __attribute__((ext_vector_type(8)));

#define DIM 128
// Spill rules (r17/r20/r21/r22, measured): (a) never wrap the MFMA block in a
// runtime loop; (b) never put MORE THAN ONE mlp_wave call in a kernel; (c) MFMA
// kernels at 4- or 8-wave blocks with __launch_bounds__(N,4) only.

__device__ __forceinline__ float fast_tanh(float x) {
    float e = __builtin_amdgcn_exp2f(x * 2.885390081777927f);
    return 1.0f - 2.0f * __builtin_amdgcn_rcpf(e + 1.0f);
}
__device__ __forceinline__ float fast_sigmoid(float x) {
    float e = __builtin_amdgcn_exp2f(x * -1.4426950408889634f);
    return __builtin_amdgcn_rcpf(1.0f + e);
}

template<int NT>
__device__ __forceinline__ void stage_w2(const float* __restrict__ W2,
                                         _Float16* sW2T, int tid) {
    #pragma unroll
    for (int s = 0; s < 2048 / NT; ++s) {
        int chunk = s * NT + tid;        // 0..2047
        int n = chunk & 127, ko = chunk >> 7;
        f16x8 v;
        #pragma unroll
        for (int qq = 0; qq < 8; ++qq)
            v[qq] = (_Float16)W2[(ko * 8 + qq) * DIM + n];   // coalesced over n
        int slot = ko ^ (n & 15);
        *(f16x8*)&sW2T[n * DIM + slot * 8] = v;
    }
}

// one wave: 32 points (2 A-frags) x 128 dims; b2 folded into acc init.
__device__ __forceinline__ void mlp_wave(
    const float xs[2], const float ys[2], const _Float16* sW2T,
    const float* __restrict__ W1, const float* __restrict__ b1,
    const float* __restrict__ b2, const float* __restrict__ W3,
    int lg, int l15, float rs[2][4])
{
    f32x4 acc[2][8];
    #pragma unroll
    for (int nf = 0; nf < 8; ++nf) {
        float b2v = b2[nf * 16 + l15];
        acc[0][nf] = (f32x4)(b2v);
        acc[1][nf] = (f32x4)(b2v);
    }
    #pragma unroll
    for (int kf = 0; kf < 4; ++kf) {
        const int kbase = kf * 32 + lg * 8;
        f16x8 bh[8];
        #pragma unroll
        for (int nf = 0; nf < 8; ++nf) {
            int cc = nf * 16 + l15;
            int slot = (kf * 4 + lg) ^ l15;   // matches stage_w2 swizzle
            bh[nf] = *(const f16x8*)&sW2T[cc * DIM + slot * 8];
        }
        f32x4 wxa = *(const f32x4*)&W1[kbase];
        f32x4 wxb = *(const f32x4*)&W1[kbase + 4];
        f32x4 wya = *(const f32x4*)&W1[DIM + kbase];
        f32x4 wyb = *(const f32x4*)&W1[DIM + kbase + 4];
        f32x4 b1a = *(const f32x4*)&b1[kbase];
        f32x4 b1b = *(const f32x4*)&b1[kbase + 4];
        f16x8 ah[2];
        #pragma unroll
        for (int mf = 0; mf < 2; ++mf) {
            float x = xs[mf], y = ys[mf];
            #pragma unroll
            for (int qq = 0; qq < 4; ++qq)
                ah[mf][qq] = (_Float16)fast_tanh(fmaf(x, wxa[qq], fmaf(y, wya[qq], b1a[qq])));
            #pragma unroll
            for (int qq = 0; qq < 4; ++qq)
                ah[mf][4 + qq] = (_Float16)fast_tanh(fmaf(x, wxb[qq], fmaf(y, wyb[qq], b1b[qq])));
        }
        #pragma unroll
        for (int nf = 0; nf < 8; ++nf)
            #pragma unroll
            for (int mf = 0; mf < 2; ++mf)
                acc[mf][nf] = __builtin_amdgcn_mfma_f32_16x16x32_f16(ah[mf], bh[nf], acc[mf][nf], 0, 0, 0);
    }
    #pragma unroll
    for (int mf = 0; mf < 2; ++mf)
        #pragma unroll
        for (int rg = 0; rg < 4; ++rg) rs[mf][rg] = 0.0f;
    #pragma unroll
    for (int nf = 0; nf < 8; ++nf) {
        float w3v = W3[nf * 16 + l15];
        #pragma unroll
        for (int mf = 0; mf < 2; ++mf)
            #pragma unroll
            for (int rg = 0; rg < 4; ++rg)
                rs[mf][rg] += fast_tanh(acc[mf][nf][rg]) * w3v;
    }
    #pragma unroll
    for (int mf = 0; mf < 2; ++mf)
        #pragma unroll
        for (int rg = 0; rg < 4; ++rg) {
            float v = rs[mf][rg];
            v += __shfl_xor(v, 1);
            v += __shfl_xor(v, 2);
            v += __shfl_xor(v, 4);
            v += __shfl_xor(v, 8);
            rs[mf][rg] = v;
        }
}

// ---- dense MLP eval of the 257 grid: 512 thr, 256 pts/block, ONE mlp_wave ----
__global__ __launch_bounds__(512, 4) void eval_grid(
    const float* __restrict__ W1, const float* __restrict__ b1,
    const float* __restrict__ W2, const float* __restrict__ b2,
    const float* __restrict__ W3, const float* __restrict__ b3,
    const float* __restrict__ bmin, const float* __restrict__ bmax,
    float* __restrict__ out, int R)
{
    __shared__ __align__(16) _Float16 sW2T[DIM * DIM];   // 32 KB
    const int N = R * R;
    const int tid = threadIdx.x;
    const int m0 = blockIdx.x * 256;
    stage_w2<512>(W2, sW2T, tid);

    const int w = tid >> 6, lane = tid & 63;   // 8 waves x 32 pts
    const int l15 = lane & 15, lg = lane >> 4;

    const float inv = 1.0f / (float)(R - 1);   // power-of-two -> exact
    const float bx0 = bmin[0], by0 = bmin[1];
    const float sx = bmax[0] - bx0, sy = bmax[1] - by0;
    float xs[2], ys[2];
    #pragma unroll
    for (int mf = 0; mf < 2; ++mf) {
        int pi = m0 + w * 32 + mf * 16 + l15;
        int pg = (pi < N) ? pi : N - 1;
        int gi = pg / R, gj = pg - gi * R;
        xs[mf] = bx0 + (float)gj * inv * sx;
        ys[mf] = by0 + (float)gi * inv * sy;
    }
    __syncthreads();

    float rs[2][4];
    mlp_wave(xs, ys, sW2T, W1, b1, b2, W3, lg, l15, rs);
    if (l15 == 0) {
        float b3v = b3[0];
        #pragma unroll
        for (int mf = 0; mf < 2; ++mf)
            #pragma unroll
            for (int rg = 0; rg < 4; ++rg) {
                int po = m0 + w * 32 + mf * 16 + lg * 4 + rg;
                if (po < N) out[po] = fast_sigmoid(rs[mf][rg] + b3v);
            }
    }
}

// ---- masked fine eval of the 513 grid: one 16x16 tile per block, 512 thr ----
__global__ __launch_bounds__(512, 4) void eval_fine(
    const float* __restrict__ W1, const float* __restrict__ b1,
    const float* __restrict__ W2, const float* __restrict__ b2,
    const float* __restrict__ W3, const float* __restrict__ b3,
    const float* __restrict__ bmin, const float* __restrict__ bmax,
    const u8* __restrict__ sgn257, float* __restrict__ q4)
{
    __shared__ __align__(16) _Float16 sW2T[DIM * DIM];
    const int bi = blockIdx.x / 33, bj = blockIdx.x - bi * 33;  // 33x33 tiles
    const int ti0 = bi * 16, tj0 = bj * 16;
    const int tid = threadIdx.x;

    const int iLo = (8 * bi - 2) < 0 ? 0 : (8 * bi - 2);
    const int iHi = (8 * bi + 10) > 256 ? 256 : (8 * bi + 10);
    const int jLo = (8 * bj - 2) < 0 ? 0 : (8 * bj - 2);
    const int jHi = (8 * bj + 10) > 256 ? 256 : (8 * bj + 10);
    const u8 ref = sgn257[iLo * 257 + jLo];
    bool diff = false;
    for (int s = tid; s < 169; s += 512) {
        int ii = iLo + s / 13, jj = jLo + s % 13;
        if (ii <= iHi && jj <= jHi)
            diff |= (sgn257[ii * 257 + jj] != ref);
    }
    if (!__syncthreads_or(diff ? 1 : 0)) return;

    stage_w2<512>(W2, sW2T, tid);
    __syncthreads();

    const int w = tid >> 6, lane = tid & 63;
    const int l15 = lane & 15, lg = lane >> 4;
    const float inv = 1.0f / 512.0f;
    const float bx0 = bmin[0], by0 = bmin[1];
    const float sx = bmax[0] - bx0, sy = bmax[1] - by0;

    float xs[2], ys[2];
    #pragma unroll
    for (int mf = 0; mf < 2; ++mf) {
        int p = w * 32 + mf * 16 + l15;        // 0..255 within tile
        int gi = ti0 + (p >> 4), gj = tj0 + (p & 15);
        if (gi > 512) gi = 512;
        if (gj > 512) gj = 512;
        xs[mf] = bx0 + (float)gj * inv * sx;
        ys[mf] = by0 + (float)gi * inv * sy;
    }
    float rs[2][4];
    mlp_wave(xs, ys, sW2T, W1, b1, b2, W3, lg, l15, rs);
    if (l15 == 0) {
        float b3v = b3[0];
        #pragma unroll
        for (int mf = 0; mf < 2; ++mf)
            #pragma unroll
            for (int rg = 0; rg < 4; ++rg) {
                int p = w * 32 + mf * 16 + lg * 4 + rg;
                int gi = ti0 + (p >> 4), gj = tj0 + (p & 15);
                if (gi < 513 && gj < 513)
                    q4[gi * 513 + gj] = fast_sigmoid(rs[mf][rg] + b3v);
            }
    }
}

// ---- one refinement level on a 24x24 window, one thread per cell ----
#define HWF 24
#define NTF 576
template<bool FIRST>
__device__ __forceinline__ void run_level(
    int c, int li, int lj, int oi0, int oj0, int R,
    const float* __restrict__ qbuf, int qpitch, int qs,
    const float* __restrict__ q257, int pOi, int pOj,
    const float* sOccP, const u8* sCalP,
    u8* sRaw, u8* sCfA, u8* sCfB,
    float& occR, bool& calR)
{
    const float BAL = 0.5f;
    const int fi = oi0 + li, fj = oj0 + lj;
    const bool inG = (fi >= 0 && fi < R && fj >= 0 && fj < R);
    float occ = 0.5f, qv = 0.5f;
    u8 rw = 0; bool cal = false;
    if (inG) qv = qbuf[(fi * qs) * qpitch + fj * qs];   // issued early, used late
    if (inG) {
        int ip = fi >> 1, jp = fj >> 1;
        int oi = fi & 1, oj = fj & 1;
        float tl = FIRST ? q257[(ip * 8) * 257 + jp * 8]
                         : sOccP[(ip - pOi) * HWF + (jp - pOj)];
        bool b;
        if (!oi && !oj) { occ = tl; b = false; }
        else if (oi && !oj) {
            float bl = FIRST ? q257[((ip + 1) * 8) * 257 + jp * 8]
                             : sOccP[(ip + 1 - pOi) * HWF + (jp - pOj)];
            occ = 0.5f * (tl + bl);
            b = (tl > BAL) != (bl > BAL);
        } else if (!oi && oj) {
            float tr = FIRST ? q257[(ip * 8) * 257 + (jp + 1) * 8]
                             : sOccP[(ip - pOi) * HWF + (jp + 1 - pOj)];
            occ = 0.5f * (tl + tr);
            b = (tl > BAL) != (tr > BAL);
        } else {
            float bl = FIRST ? q257[((ip + 1) * 8) * 257 + jp * 8]
                             : sOccP[(ip + 1 - pOi) * HWF + (jp - pOj)];
            float tr = FIRST ? q257[(ip * 8) * 257 + (jp + 1) * 8]
                             : sOccP[(ip - pOi) * HWF + (jp + 1 - pOj)];
            float br = FIRST ? q257[((ip + 1) * 8) * 257 + (jp + 1) * 8]
                             : sOccP[(ip + 1 - pOi) * HWF + (jp + 1 - pOj)];
            occ = 0.5f * (0.5f * (tl + bl) + 0.5f * (tr + br));  // exact _up2 order
            bool m0 = tl > BAL, m1 = bl > BAL, m2 = tr > BAL, m3 = br > BAL;
            b = (m0 | m1 | m2 | m3) && !(m0 & m1 & m2 & m3);
        }
        rw = b ? 1 : 0;
        if (((fi | fj) & 1) == 0)
            cal = FIRST ? true : (sCalP[(ip - pOi) * HWF + (jp - pOj)] != 0);
    }
    sRaw[c] = rw; sCfA[c] = 0; sCfB[c] = 0;

    if (__syncthreads_or(rw)) {
        u8 cf = 0;
        if (li >= 1 && li < HWF - 1 && lj >= 1 && lj < HWF - 1 && inG) {
            bool b = false;
            #pragma unroll
            for (int di = -1; di <= 1; ++di)
                #pragma unroll
                for (int dj = -1; dj <= 1; ++dj)
                    if (sRaw[(li + di) * HWF + (lj + dj)]) b = true;
            b = b && !cal;
            cf = (b && (occ - BAL) * (qv - BAL) < 0.0f) ? 1 : 0;
            if (b) { occ = qv; cal = true; }
            sCfA[c] = cf;
        }
        int haveCf = __syncthreads_or((int)cf);

        #pragma unroll
        for (int it = 0; it < 3; ++it) {
            if (!haveCf) break;
            const u8* cin = (it & 1) ? sCfB : sCfA;
            u8* cout      = (it & 1) ? sCfA : sCfB;
            int lo = 2 + it, hi = HWF - 2 - it;
            u8 nc = 0;
            if (li >= lo && li < hi && lj >= lo && lj < hi && inG) {
                bool any = false;
                #pragma unroll
                for (int di = -1; di <= 1; ++di)
                    #pragma unroll
                    for (int dj = -1; dj <= 1; ++dj)
                        if (cin[(li + di) * HWF + (lj + dj)]) any = true;
                bool cand = any && !cal;
                nc = (cand && (occ - BAL) * (qv - BAL) < 0.0f) ? 1 : 0;
                if (cand) { occ = qv; cal = true; }
                cout[c] = nc;
            }
            haveCf = __syncthreads_or((int)nc);
        }
    }
    occR = occ; calR = cal;
}

// ---- levels 1-3 fused, one block per 16x16 tile of the 257 grid ----
__global__ __launch_bounds__(NTF) void levels123_fused(
    const float* __restrict__ q257,
    float* __restrict__ occ257, u8* __restrict__ cal257,
    u8* __restrict__ sgn257)
{
    __shared__ float sOcc[NTF];
    __shared__ u8 sCal[NTF], sRaw[NTF], sCfA[NTF], sCfB[NTF];
    const int bi = blockIdx.x / 17, bj = blockIdx.x - bi * 17;
    const int c = threadIdx.x;
    const int li = c / HWF, lj = c - li * HWF;
    float occ; bool cal;

    run_level<true>(c, li, lj, 4 * bi - 7, 4 * bj - 7, 65,
                    q257, 257, 4, q257, 0, 0,
                    sOcc, sCal, sRaw, sCfA, sCfB, occ, cal);
    sOcc[c] = occ; sCal[c] = cal ? 1 : 0;
    __syncthreads();
    run_level<false>(c, li, lj, 8 * bi - 6, 8 * bj - 6, 129,
                     q257, 257, 2, q257, 4 * bi - 7, 4 * bj - 7,
                     sOcc, sCal, sRaw, sCfA, sCfB, occ, cal);
    sOcc[c] = occ; sCal[c] = cal ? 1 : 0;
    __syncthreads();
    run_level<false>(c, li, lj, 16 * bi - 4, 16 * bj - 4, 257,
                     q257, 257, 1, q257, 8 * bi - 6, 8 * bj - 6,
                     sOcc, sCal, sRaw, sCfA, sCfB, occ, cal);

    const int fi = 16 * bi - 4 + li, fj = 16 * bj - 4 + lj;
    if (li >= 4 && li < 20 && lj >= 4 && lj < 20 && fi < 257 && fj < 257) {
        occ257[fi * 257 + fj] = occ;
        cal257[fi * 257 + fj] = cal ? 1 : 0;
        sgn257[fi * 257 + fj] = (occ > 0.5f) ? 1 : 0;
    }
}

// ---- level 4: TS=24 tiles of 513 (484 blocks, 1024 thr, 1 thread/cell) ----
#define TS4 24
#define HW4 32
__global__ __launch_bounds__(1024) void level4_kernel(
    const float* __restrict__ occP, const u8* __restrict__ calcP,
    const u8* __restrict__ sgn257,
    const float* __restrict__ q4, float* __restrict__ out)
{
    __shared__ u8 sRaw[HW4 * HW4], sCfA[HW4 * HW4], sCfB[HW4 * HW4];
    const int nT = 22;                       // ceil(513/24)
    const int bi = blockIdx.x / nT, bj = blockIdx.x - bi * nT;
    const int fi0 = bi * TS4 - 4, fj0 = bj * TS4 - 4;
    const int c = threadIdx.x;
    const int li = c / HW4, lj = c - li * HW4;
    const int fi = fi0 + li, fj = fj0 + lj;
    const bool inG = (fi >= 0 && fi < 513 && fj >= 0 && fj < 513);
    const float BAL = 0.5f;

    const int iLo = (12 * bi - 3) < 0 ? 0 : (12 * bi - 3);
    const int iHi = (12 * bi + 14) > 256 ? 256 : (12 * bi + 14);
    const int jLo = (12 * bj - 3) < 0 ? 0 : (12 * bj - 3);
    const int jHi = (12 * bj + 14) > 256 ? 256 : (12 * bj + 14);
    bool diff = false;
    if (c < 324) {
        int ii = iLo + c / 18, jj = jLo + c % 18;
        if (ii <= iHi && jj <= jHi)
            diff = (sgn257[ii * 257 + jj] != sgn257[iLo * 257 + jLo]);
    }
    const bool needFull = __syncthreads_or(diff ? 1 : 0);

    float occ = 0.5f;
    u8 rw = 0; bool cal = false;
    if (inG) {
        int ip = fi >> 1, jp = fj >> 1;
        float tl = occP[ip * 257 + jp];
        int oi = fi & 1, oj = fj & 1;
        bool b = false;
        if (!oi && !oj) { occ = tl; }
        else if (oi && !oj) {
            float bl = occP[(ip + 1) * 257 + jp];
            occ = 0.5f * (tl + bl);
            b = (tl > BAL) != (bl > BAL);
        } else if (!oi && oj) {
            float tr = occP[ip * 257 + jp + 1];
            occ = 0.5f * (tl + tr);
            b = (tl > BAL) != (tr > BAL);
        } else {
            float bl = occP[(ip + 1) * 257 + jp];
            float tr = occP[ip * 257 + jp + 1];
            float br = occP[(ip + 1) * 257 + jp + 1];
            occ = 0.5f * (0.5f * (tl + bl) + 0.5f * (tr + br));  // exact _up2 order
            bool m0 = tl > BAL, m1 = bl > BAL, m2 = tr > BAL, m3 = br > BAL;
            b = (m0 | m1 | m2 | m3) && !(m0 & m1 & m2 & m3);
        }
        rw = (needFull && b) ? 1 : 0;
        if (((fi | fj) & 1) == 0) cal = calcP[ip * 257 + jp] != 0;
    }

    if (needFull) {
        sRaw[c] = rw; sCfA[c] = 0; sCfB[c] = 0;
        if (__syncthreads_or(rw)) {
            const float qv = inG ? q4[fi * 513 + fj] : 0.5f;
            u8 cf = 0;
            if (li >= 1 && li < HW4 - 1 && lj >= 1 && lj < HW4 - 1 && inG) {
                bool b = false;
                #pragma unroll
                for (int di = -1; di <= 1; ++di)
                    #pragma unroll
                    for (int dj = -1; dj <= 1; ++dj)
                        if (sRaw[(li + di) * HW4 + (lj + dj)]) b = true;
                b = b && !cal;
                cf = (b && (occ - BAL) * (qv - BAL) < 0.0f) ? 1 : 0;
                if (b) { occ = qv; cal = true; }
                sCfA[c] = cf;
            }
            int haveCf = __syncthreads_or((int)cf);

            #pragma unroll
            for (int it = 0; it < 3; ++it) {
                if (!haveCf) break;
                const u8* cin = (it & 1) ? sCfB : sCfA;
                u8* cout      = (it & 1) ? sCfA : sCfB;
                int lo = 2 + it, hi = HW4 - 2 - it;
                u8 nc = 0;
                if (li >= lo && li < hi && lj >= lo && lj < hi && inG) {
                    bool any = false;
                    #pragma unroll
                    for (int di = -1; di <= 1; ++di)
                        #pragma unroll
                        for (int dj = -1; dj <= 1; ++dj)
                            if (cin[(li + di) * HW4 + (lj + dj)]) any = true;
                    bool cand = any && !cal;
                    nc = (cand && (occ - BAL) * (qv - BAL) < 0.0f) ? 1 : 0;
                    if (cand) { occ = qv; cal = true; }
                    cout[c] = nc;
                }
                haveCf = __syncthreads_or((int)nc);
            }
        }
    }

    if (li >= 4 && li < 4 + TS4 && lj >= 4 && lj < 4 + TS4 && inG)
        out[fi * 513 + fj] = occ;
}

extern "C" void kernel_launch(void* const* d_in, const int* in_sizes, int n_in,
                              void* d_out, int out_size, void* d_ws, size_t ws_size,
                              hipStream_t stream) {
    const float* W1   = (const float*)d_in[0];
    const float* b1   = (const float*)d_in[1];
    const float* W2   = (const float*)d_in[2];
    const float* b2   = (const float*)d_in[3];
    const float* W3   = (const float*)d_in[4];
    const float* b3   = (const float*)d_in[5];
    const float* bmin = (const float*)d_in[6];
    const float* bmax = (const float*)d_in[7];

    const int N513 = 513 * 513, N257 = 257 * 257;
    float* q257   = (float*)d_ws;
    float* occ257 = q257 + N257;
    float* q4     = occ257 + N257;
    u8*    cal257 = (u8*)(q4 + N513);
    u8*    sgn257 = cal257 + N257;
    float* out    = (float*)d_out;

    // 1) dense eval at 257 (512-thr blocks, 256 pts each -> 259 blocks)
    eval_grid<<<(N257 + 255) / 256, 512, 0, stream>>>(
        W1, b1, W2, b2, W3, b3, bmin, bmax, q257, 257);

    // 2) levels 1-3 fused -> refined occ257 + cal257 + sgn257
    levels123_fused<<<17 * 17, NTF, 0, stream>>>(q257, occ257, cal257, sgn257);

    // 3) masked fine eval of the 513 grid (sign-mask need-check)
    eval_fine<<<33 * 33, 512, 0, stream>>>(
        W1, b1, W2, b2, W3, b3, bmin, bmax, sgn257, q4);

    // 4) level 4 -> output (TS=24, 484 blocks, sgn pre-check)
    level4_kernel<<<22 * 22, 1024, 0, stream>>>(occ257, cal257, sgn257, q4, out);
}

// Round 27
// 43.025 us; speedup vs baseline: 1.0374x; 1.0374x over previous
//
#include <hip/hip_runtime.h>

typedef unsigned char u8;
typedef float f32x4 __attribute__((ext_vector_type(4)));
typedef _Float16 f16x8 __attribute__((ext_vector_type(8)));

#define DIM 128
#define TM  128
// Spill rules (r17/r20/r21/r22, measured): (a) never wrap the MFMA block in a
// runtime loop; (b) never put MORE THAN ONE mlp_wave call in a kernel; (c) MFMA
// kernels at 4- or 8-wave blocks with __launch_bounds__(N,4) only.
// Shape rules (r10/r11/r26, measured): eval at 256 thr/TM=128 (mf=2) is the
// occupancy sweet spot; 512-thr dense eval packs worse (r26 +1.6us).

__device__ __forceinline__ float fast_tanh(float x) {
    float e = __builtin_amdgcn_exp2f(x * 2.885390081777927f);
    return 1.0f - 2.0f * __builtin_amdgcn_rcpf(e + 1.0f);
}
__device__ __forceinline__ float fast_sigmoid(float x) {
    float e = __builtin_amdgcn_exp2f(x * -1.4426950408889634f);
    return __builtin_amdgcn_rcpf(1.0f + e);
}

template<int NT>
__device__ __forceinline__ void stage_w2(const float* __restrict__ W2,
                                         _Float16* sW2T, int tid) {
    #pragma unroll
    for (int s = 0; s < 2048 / NT; ++s) {
        int chunk = s * NT + tid;        // 0..2047
        int n = chunk & 127, ko = chunk >> 7;
        f16x8 v;
        #pragma unroll
        for (int qq = 0; qq < 8; ++qq)
            v[qq] = (_Float16)W2[(ko * 8 + qq) * DIM + n];   // coalesced over n
        int slot = ko ^ (n & 15);
        *(f16x8*)&sW2T[n * DIM + slot * 8] = v;
    }
}

// one wave: 32 points (2 A-frags) x 128 dims; b2 folded into acc init.
__device__ __forceinline__ void mlp_wave(
    const float xs[2], const float ys[2], const _Float16* sW2T,
    const float* __restrict__ W1, const float* __restrict__ b1,
    const float* __restrict__ b2, const float* __restrict__ W3,
    int lg, int l15, float rs[2][4])
{
    f32x4 acc[2][8];
    #pragma unroll
    for (int nf = 0; nf < 8; ++nf) {
        float b2v = b2[nf * 16 + l15];
        acc[0][nf] = (f32x4)(b2v);
        acc[1][nf] = (f32x4)(b2v);
    }
    #pragma unroll
    for (int kf = 0; kf < 4; ++kf) {
        const int kbase = kf * 32 + lg * 8;
        f16x8 bh[8];
        #pragma unroll
        for (int nf = 0; nf < 8; ++nf) {
            int cc = nf * 16 + l15;
            int slot = (kf * 4 + lg) ^ l15;   // matches stage_w2 swizzle
            bh[nf] = *(const f16x8*)&sW2T[cc * DIM + slot * 8];
        }
        f32x4 wxa = *(const f32x4*)&W1[kbase];
        f32x4 wxb = *(const f32x4*)&W1[kbase + 4];
        f32x4 wya = *(const f32x4*)&W1[DIM + kbase];
        f32x4 wyb = *(const f32x4*)&W1[DIM + kbase + 4];
        f32x4 b1a = *(const f32x4*)&b1[kbase];
        f32x4 b1b = *(const f32x4*)&b1[kbase + 4];
        f16x8 ah[2];
        #pragma unroll
        for (int mf = 0; mf < 2; ++mf) {
            float x = xs[mf], y = ys[mf];
            #pragma unroll
            for (int qq = 0; qq < 4; ++qq)
                ah[mf][qq] = (_Float16)fast_tanh(fmaf(x, wxa[qq], fmaf(y, wya[qq], b1a[qq])));
            #pragma unroll
            for (int qq = 0; qq < 4; ++qq)
                ah[mf][4 + qq] = (_Float16)fast_tanh(fmaf(x, wxb[qq], fmaf(y, wyb[qq], b1b[qq])));
        }
        #pragma unroll
        for (int nf = 0; nf < 8; ++nf)
            #pragma unroll
            for (int mf = 0; mf < 2; ++mf)
                acc[mf][nf] = __builtin_amdgcn_mfma_f32_16x16x32_f16(ah[mf], bh[nf], acc[mf][nf], 0, 0, 0);
    }
    #pragma unroll
    for (int mf = 0; mf < 2; ++mf)
        #pragma unroll
        for (int rg = 0; rg < 4; ++rg) rs[mf][rg] = 0.0f;
    #pragma unroll
    for (int nf = 0; nf < 8; ++nf) {
        float w3v = W3[nf * 16 + l15];
        #pragma unroll
        for (int mf = 0; mf < 2; ++mf)
            #pragma unroll
            for (int rg = 0; rg < 4; ++rg)
                rs[mf][rg] += fast_tanh(acc[mf][nf][rg]) * w3v;
    }
    #pragma unroll
    for (int mf = 0; mf < 2; ++mf)
        #pragma unroll
        for (int rg = 0; rg < 4; ++rg) {
            float v = rs[mf][rg];
            v += __shfl_xor(v, 1);
            v += __shfl_xor(v, 2);
            v += __shfl_xor(v, 4);
            v += __shfl_xor(v, 8);
            rs[mf][rg] = v;
        }
}

// ---- dense MLP eval of an RxR grid (R-1 power of two); straight-line ----
__global__ __launch_bounds__(256, 4) void eval_grid(
    const float* __restrict__ W1, const float* __restrict__ b1,
    const float* __restrict__ W2, const float* __restrict__ b2,
    const float* __restrict__ W3, const float* __restrict__ b3,
    const float* __restrict__ bmin, const float* __restrict__ bmax,
    float* __restrict__ out, int R)
{
    __shared__ __align__(16) _Float16 sW2T[DIM * DIM];   // 32 KB
    const int N = R * R;
    const int tid = threadIdx.x;
    const int m0 = blockIdx.x * TM;
    stage_w2<256>(W2, sW2T, tid);

    const int w = tid >> 6, lane = tid & 63;
    const int l15 = lane & 15, lg = lane >> 4;

    const float inv = 1.0f / (float)(R - 1);   // power-of-two -> exact
    const float bx0 = bmin[0], by0 = bmin[1];
    const float sx = bmax[0] - bx0, sy = bmax[1] - by0;
    float xs[2], ys[2];
    #pragma unroll
    for (int mf = 0; mf < 2; ++mf) {
        int pi = m0 + w * 32 + mf * 16 + l15;
        int pg = (pi < N) ? pi : N - 1;
        int gi = pg / R, gj = pg - gi * R;
        xs[mf] = bx0 + (float)gj * inv * sx;
        ys[mf] = by0 + (float)gi * inv * sy;
    }
    __syncthreads();

    float rs[2][4];
    mlp_wave(xs, ys, sW2T, W1, b1, b2, W3, lg, l15, rs);
    if (l15 == 0) {
        float b3v = b3[0];
        #pragma unroll
        for (int mf = 0; mf < 2; ++mf)
            #pragma unroll
            for (int rg = 0; rg < 4; ++rg) {
                int po = m0 + w * 32 + mf * 16 + lg * 4 + rg;
                if (po < N) out[po] = fast_sigmoid(rs[mf][rg] + b3v);
            }
    }
}

// ---- masked fine eval of the 513 grid: one 16x16 tile per block, 512 thr ----
__global__ __launch_bounds__(512, 4) void eval_fine(
    const float* __restrict__ W1, const float* __restrict__ b1,
    const float* __restrict__ W2, const float* __restrict__ b2,
    const float* __restrict__ W3, const float* __restrict__ b3,
    const float* __restrict__ bmin, const float* __restrict__ bmax,
    const u8* __restrict__ sgn257, float* __restrict__ q4)
{
    __shared__ __align__(16) _Float16 sW2T[DIM * DIM];
    const int bi = blockIdx.x / 33, bj = blockIdx.x - bi * 33;  // 33x33 tiles
    const int ti0 = bi * 16, tj0 = bj * 16;
    const int tid = threadIdx.x;

    const int iLo = (8 * bi - 2) < 0 ? 0 : (8 * bi - 2);
    const int iHi = (8 * bi + 10) > 256 ? 256 : (8 * bi + 10);
    const int jLo = (8 * bj - 2) < 0 ? 0 : (8 * bj - 2);
    const int jHi = (8 * bj + 10) > 256 ? 256 : (8 * bj + 10);
    const u8 ref = sgn257[iLo * 257 + jLo];
    bool diff = false;
    for (int s = tid; s < 169; s += 512) {
        int ii = iLo + s / 13, jj = jLo + s % 13;
        if (ii <= iHi && jj <= jHi)
            diff |= (sgn257[ii * 257 + jj] != ref);
    }
    if (!__syncthreads_or(diff ? 1 : 0)) return;

    stage_w2<512>(W2, sW2T, tid);
    __syncthreads();

    const int w = tid >> 6, lane = tid & 63;
    const int l15 = lane & 15, lg = lane >> 4;
    const float inv = 1.0f / 512.0f;
    const float bx0 = bmin[0], by0 = bmin[1];
    const float sx = bmax[0] - bx0, sy = bmax[1] - by0;

    float xs[2], ys[2];
    #pragma unroll
    for (int mf = 0; mf < 2; ++mf) {
        int p = w * 32 + mf * 16 + l15;        // 0..255 within tile
        int gi = ti0 + (p >> 4), gj = tj0 + (p & 15);
        if (gi > 512) gi = 512;
        if (gj > 512) gj = 512;
        xs[mf] = bx0 + (float)gj * inv * sx;
        ys[mf] = by0 + (float)gi * inv * sy;
    }
    float rs[2][4];
    mlp_wave(xs, ys, sW2T, W1, b1, b2, W3, lg, l15, rs);
    if (l15 == 0) {
        float b3v = b3[0];
        #pragma unroll
        for (int mf = 0; mf < 2; ++mf)
            #pragma unroll
            for (int rg = 0; rg < 4; ++rg) {
                int p = w * 32 + mf * 16 + lg * 4 + rg;
                int gi = ti0 + (p >> 4), gj = tj0 + (p & 15);
                if (gi < 513 && gj < 513)
                    q4[gi * 513 + gj] = fast_sigmoid(rs[mf][rg] + b3v);
            }
    }
}

// ---- one refinement level on a 24x24 window, one thread per cell ----
#define HWF 24
#define NTF 576
template<bool FIRST>
__device__ __forceinline__ void run_level(
    int c, int li, int lj, int oi0, int oj0, int R,
    const float* __restrict__ qbuf, int qpitch, int qs,
    const float* __restrict__ q257, int pOi, int pOj,
    const float* sOccP, const u8* sCalP,
    u8* sRaw, u8* sCfA, u8* sCfB,
    float& occR, bool& calR)
{
    const float BAL = 0.5f;
    const int fi = oi0 + li, fj = oj0 + lj;
    const bool inG = (fi >= 0 && fi < R && fj >= 0 && fj < R);
    float occ = 0.5f, qv = 0.5f;
    u8 rw = 0; bool cal = false;
    if (inG) qv = qbuf[(fi * qs) * qpitch + fj * qs];   // issued early, used late
    if (inG) {
        int ip = fi >> 1, jp = fj >> 1;
        int oi = fi & 1, oj = fj & 1;
        float tl = FIRST ? q257[(ip * 8) * 257 + jp * 8]
                         : sOccP[(ip - pOi) * HWF + (jp - pOj)];
        bool b;
        if (!oi && !oj) { occ = tl; b = false; }
        else if (oi && !oj) {
            float bl = FIRST ? q257[((ip + 1) * 8) * 257 + jp * 8]
                             : sOccP[(ip + 1 - pOi) * HWF + (jp - pOj)];
            occ = 0.5f * (tl + bl);
            b = (tl > BAL) != (bl > BAL);
        } else if (!oi && oj) {
            float tr = FIRST ? q257[(ip * 8) * 257 + (jp + 1) * 8]
                             : sOccP[(ip - pOi) * HWF + (jp + 1 - pOj)];
            occ = 0.5f * (tl + tr);
            b = (tl > BAL) != (tr > BAL);
        } else {
            float bl = FIRST ? q257[((ip + 1) * 8) * 257 + jp * 8]
                             : sOccP[(ip + 1 - pOi) * HWF + (jp - pOj)];
            float tr = FIRST ? q257[(ip * 8) * 257 + (jp + 1) * 8]
                             : sOccP[(ip - pOi) * HWF + (jp + 1 - pOj)];
            float br = FIRST ? q257[((ip + 1) * 8) * 257 + (jp + 1) * 8]
                             : sOccP[(ip + 1 - pOi) * HWF + (jp + 1 - pOj)];
            occ = 0.5f * (0.5f * (tl + bl) + 0.5f * (tr + br));  // exact _up2 order
            bool m0 = tl > BAL, m1 = bl > BAL, m2 = tr > BAL, m3 = br > BAL;
            b = (m0 | m1 | m2 | m3) && !(m0 & m1 & m2 & m3);
        }
        rw = b ? 1 : 0;
        if (((fi | fj) & 1) == 0)
            cal = FIRST ? true : (sCalP[(ip - pOi) * HWF + (jp - pOj)] != 0);
    }
    sRaw[c] = rw; sCfA[c] = 0; sCfB[c] = 0;

    if (__syncthreads_or(rw)) {
        u8 cf = 0;
        if (li >= 1 && li < HWF - 1 && lj >= 1 && lj < HWF - 1 && inG) {
            bool b = false;
            #pragma unroll
            for (int di = -1; di <= 1; ++di)
                #pragma unroll
                for (int dj = -1; dj <= 1; ++dj)
                    if (sRaw[(li + di) * HWF + (lj + dj)]) b = true;
            b = b && !cal;
            cf = (b && (occ - BAL) * (qv - BAL) < 0.0f) ? 1 : 0;
            if (b) { occ = qv; cal = true; }
            sCfA[c] = cf;
        }
        int haveCf = __syncthreads_or((int)cf);

        #pragma unroll
        for (int it = 0; it < 3; ++it) {
            if (!haveCf) break;
            const u8* cin = (it & 1) ? sCfB : sCfA;
            u8* cout      = (it & 1) ? sCfA : sCfB;
            int lo = 2 + it, hi = HWF - 2 - it;
            u8 nc = 0;
            if (li >= lo && li < hi && lj >= lo && lj < hi && inG) {
                bool any = false;
                #pragma unroll
                for (int di = -1; di <= 1; ++di)
                    #pragma unroll
                    for (int dj = -1; dj <= 1; ++dj)
                        if (cin[(li + di) * HWF + (lj + dj)]) any = true;
                bool cand = any && !cal;
                nc = (cand && (occ - BAL) * (qv - BAL) < 0.0f) ? 1 : 0;
                if (cand) { occ = qv; cal = true; }
                cout[c] = nc;
            }
            haveCf = __syncthreads_or((int)nc);
        }
    }
    occR = occ; calR = cal;
}

// ---- levels 1-3 fused, one block per 16x16 tile of the 257 grid ----
__global__ __launch_bounds__(NTF) void levels123_fused(
    const float* __restrict__ q257,
    float* __restrict__ occ257, u8* __restrict__ cal257,
    u8* __restrict__ sgn257)
{
    __shared__ float sOcc[NTF];
    __shared__ u8 sCal[NTF], sRaw[NTF], sCfA[NTF], sCfB[NTF];
    const int bi = blockIdx.x / 17, bj = blockIdx.x - bi * 17;
    const int c = threadIdx.x;
    const int li = c / HWF, lj = c - li * HWF;
    float occ; bool cal;

    run_level<true>(c, li, lj, 4 * bi - 7, 4 * bj - 7, 65,
                    q257, 257, 4, q257, 0, 0,
                    sOcc, sCal, sRaw, sCfA, sCfB, occ, cal);
    sOcc[c] = occ; sCal[c] = cal ? 1 : 0;
    __syncthreads();
    run_level<false>(c, li, lj, 8 * bi - 6, 8 * bj - 6, 129,
                     q257, 257, 2, q257, 4 * bi - 7, 4 * bj - 7,
                     sOcc, sCal, sRaw, sCfA, sCfB, occ, cal);
    sOcc[c] = occ; sCal[c] = cal ? 1 : 0;
    __syncthreads();
    run_level<false>(c, li, lj, 16 * bi - 4, 16 * bj - 4, 257,
                     q257, 257, 1, q257, 8 * bi - 6, 8 * bj - 6,
                     sOcc, sCal, sRaw, sCfA, sCfB, occ, cal);

    const int fi = 16 * bi - 4 + li, fj = 16 * bj - 4 + lj;
    if (li >= 4 && li < 20 && lj >= 4 && lj < 20 && fi < 257 && fj < 257) {
        occ257[fi * 257 + fj] = occ;
        cal257[fi * 257 + fj] = cal ? 1 : 0;
        sgn257[fi * 257 + fj] = (occ > 0.5f) ? 1 : 0;
    }
}

// ---- level 4: TS=24 tiles of 513 (484 blocks, 1024 thr, 1 thread/cell) ----
#define TS4 24
#define HW4 32
__global__ __launch_bounds__(1024) void level4_kernel(
    const float* __restrict__ occP, const u8* __restrict__ calcP,
    const u8* __restrict__ sgn257,
    const float* __restrict__ q4, float* __restrict__ out)
{
    __shared__ u8 sRaw[HW4 * HW4], sCfA[HW4 * HW4], sCfB[HW4 * HW4];
    const int nT = 22;                       // ceil(513/24)
    const int bi = blockIdx.x / nT, bj = blockIdx.x - bi * nT;
    const int fi0 = bi * TS4 - 4, fj0 = bj * TS4 - 4;
    const int c = threadIdx.x;
    const int li = c / HW4, lj = c - li * HW4;
    const int fi = fi0 + li, fj = fj0 + lj;
    const bool inG = (fi >= 0 && fi < 513 && fj >= 0 && fj < 513);
    const float BAL = 0.5f;

    const int iLo = (12 * bi - 3) < 0 ? 0 : (12 * bi - 3);
    const int iHi = (12 * bi + 14) > 256 ? 256 : (12 * bi + 14);
    const int jLo = (12 * bj - 3) < 0 ? 0 : (12 * bj - 3);
    const int jHi = (12 * bj + 14) > 256 ? 256 : (12 * bj + 14);
    bool diff = false;
    if (c < 324) {
        int ii = iLo + c / 18, jj = jLo + c % 18;
        if (ii <= iHi && jj <= jHi)
            diff = (sgn257[ii * 257 + jj] != sgn257[iLo * 257 + jLo]);
    }
    const bool needFull = __syncthreads_or(diff ? 1 : 0);

    float occ = 0.5f;
    u8 rw = 0; bool cal = false;
    if (inG) {
        int ip = fi >> 1, jp = fj >> 1;
        float tl = occP[ip * 257 + jp];
        int oi = fi & 1, oj = fj & 1;
        bool b = false;
        if (!oi && !oj) { occ = tl; }
        else if (oi && !oj) {
            float bl = occP[(ip + 1) * 257 + jp];
            occ = 0.5f * (tl + bl);
            b = (tl > BAL) != (bl > BAL);
        } else if (!oi && oj) {
            float tr = occP[ip * 257 + jp + 1];
            occ = 0.5f * (tl + tr);
            b = (tl > BAL) != (tr > BAL);
        } else {
            float bl = occP[(ip + 1) * 257 + jp];
            float tr = occP[ip * 257 + jp + 1];
            float br = occP[(ip + 1) * 257 + jp + 1];
            occ = 0.5f * (0.5f * (tl + bl) + 0.5f * (tr + br));  // exact _up2 order
            bool m0 = tl > BAL, m1 = bl > BAL, m2 = tr > BAL, m3 = br > BAL;
            b = (m0 | m1 | m2 | m3) && !(m0 & m1 & m2 & m3);
        }
        rw = (needFull && b) ? 1 : 0;
        if (((fi | fj) & 1) == 0) cal = calcP[ip * 257 + jp] != 0;
    }

    if (needFull) {
        sRaw[c] = rw; sCfA[c] = 0; sCfB[c] = 0;
        if (__syncthreads_or(rw)) {
            const float qv = inG ? q4[fi * 513 + fj] : 0.5f;
            u8 cf = 0;
            if (li >= 1 && li < HW4 - 1 && lj >= 1 && lj < HW4 - 1 && inG) {
                bool b = false;
                #pragma unroll
                for (int di = -1; di <= 1; ++di)
                    #pragma unroll
                    for (int dj = -1; dj <= 1; ++dj)
                        if (sRaw[(li + di) * HW4 + (lj + dj)]) b = true;
                b = b && !cal;
                cf = (b && (occ - BAL) * (qv - BAL) < 0.0f) ? 1 : 0;
                if (b) { occ = qv; cal = true; }
                sCfA[c] = cf;
            }
            int haveCf = __syncthreads_or((int)cf);

            #pragma unroll
            for (int it = 0; it < 3; ++it) {
                if (!haveCf) break;
                const u8* cin = (it & 1) ? sCfB : sCfA;
                u8* cout      = (it & 1) ? sCfA : sCfB;
                int lo = 2 + it, hi = HW4 - 2 - it;
                u8 nc = 0;
                if (li >= lo && li < hi && lj >= lo && lj < hi && inG) {
                    bool any = false;
                    #pragma unroll
                    for (int di = -1; di <= 1; ++di)
                        #pragma unroll
                        for (int dj = -1; dj <= 1; ++dj)
                            if (cin[(li + di) * HW4 + (lj + dj)]) any = true;
                    bool cand = any && !cal;
                    nc = (cand && (occ - BAL) * (qv - BAL) < 0.0f) ? 1 : 0;
                    if (cand) { occ = qv; cal = true; }
                    cout[c] = nc;
                }
                haveCf = __syncthreads_or((int)nc);
            }
        }
    }

    if (li >= 4 && li < 4 + TS4 && lj >= 4 && lj < 4 + TS4 && inG)
        out[fi * 513 + fj] = occ;
}

extern "C" void kernel_launch(void* const* d_in, const int* in_sizes, int n_in,
                              void* d_out, int out_size, void* d_ws, size_t ws_size,
                              hipStream_t stream) {
    const float* W1   = (const float*)d_in[0];
    const float* b1   = (const float*)d_in[1];
    const float* W2   = (const float*)d_in[2];
    const float* b2   = (const float*)d_in[3];
    const float* W3   = (const float*)d_in[4];
    const float* b3   = (const float*)d_in[5];
    const float* bmin = (const float*)d_in[6];
    const float* bmax = (const float*)d_in[7];

    const int N513 = 513 * 513, N257 = 257 * 257;
    float* q257   = (float*)d_ws;
    float* occ257 = q257 + N257;
    float* q4     = occ257 + N257;
    u8*    cal257 = (u8*)(q4 + N513);
    u8*    sgn257 = cal257 + N257;
    float* out    = (float*)d_out;

    // 1) dense eval at 257 (covers all q-reads of levels 1-3 bit-exactly)
    eval_grid<<<(N257 + TM - 1) / TM, 256, 0, stream>>>(
        W1, b1, W2, b2, W3, b3, bmin, bmax, q257, 257);

    // 2) levels 1-3 fused -> refined occ257 + cal257 + sgn257
    levels123_fused<<<17 * 17, NTF, 0, stream>>>(q257, occ257, cal257, sgn257);

    // 3) masked fine eval of the 513 grid (sign-mask need-check)
    eval_fine<<<33 * 33, 512, 0, stream>>>(
        W1, b1, W2, b2, W3, b3, bmin, bmax, sgn257, q4);

    // 4) level 4 -> output (TS=24, 484 blocks, sgn pre-check)
    level4_kernel<<<22 * 22, 1024, 0, stream>>>(occ257, cal257, sgn257, q4, out);
}